// Round 9
// baseline (125.432 us; speedup 1.0000x reference)
//
#include <hip/hip_runtime.h>
#include <math.h>

#define VOCAB 50000
#define EMBED 128
#define SEQ   200
#define HID   30
#define BATCH 4096

// r8 POST-MORTEM: r6/r8 failed at an IDENTICAL deterministic 3.125e-2 across
// different embproj kernels and wave counts -> real value bug, not chaos.
// (Passing kernels score absmax 0.0 vs numpy despite __expf-tanh, so the
// recurrence does NOT amplify ulp-level differences; "drift" was a wrong
// theory.) Prime suspect: TBAA -- hL is written as float but read as float4;
// the compiler may treat these as non-aliasing and hoist the next step's
// ds_read_b128 above the current step's ds_write (one-step-stale h, ~1e-2
// error, deterministic). Fix: alias-safe __builtin_memcpy reads + compiler
// memory fences around the h store. Structure otherwise identical to r8.
#define COMPILER_FENCE() asm volatile("" ::: "memory")

__device__ __forceinline__ float tanh_fast(float x) {
    // tanh(x) = 1 - 2/(e^{2x}+1); IEEE divide (NOT __fdividef - accuracy).
    float e = __expf(2.0f * x);
    return 1.0f - 2.0f / (e + 1.0f);
}

// Kernel 1: embP[v][j] = sum_e emb[v][e] * Wx[e][j] + b_rnn[j]
// BYTE-IDENTICAL to the round-4/7 pass. Do not touch.
__global__ __launch_bounds__(256) void embproj_kernel(
    const float* __restrict__ emb, const float* __restrict__ Wx,
    const float* __restrict__ brnn, float* __restrict__ embP)
{
    __shared__ float WxL[EMBED * HID];
    __shared__ float bL[32];
    int tid = threadIdx.x;
    for (int i = tid; i < EMBED * HID; i += 256) WxL[i] = Wx[i];
    if (tid < HID) bL[tid] = brnn[tid];
    __syncthreads();

    int g  = tid >> 5;
    int j  = tid & 31;
    int jj = (j < HID) ? j : 0;        // clamp LDS column for pad lanes
    int v0 = blockIdx.x * 32 + g * 4;

    int vr0 = min(v0 + 0, VOCAB - 1);
    int vr1 = min(v0 + 1, VOCAB - 1);
    int vr2 = min(v0 + 2, VOCAB - 1);
    int vr3 = min(v0 + 3, VOCAB - 1);
    const float4* e0 = (const float4*)(emb + (size_t)vr0 * EMBED);
    const float4* e1 = (const float4*)(emb + (size_t)vr1 * EMBED);
    const float4* e2 = (const float4*)(emb + (size_t)vr2 * EMBED);
    const float4* e3 = (const float4*)(emb + (size_t)vr3 * EMBED);

    float bj = (j < HID) ? bL[jj] : 0.0f;
    float acc[4][4];
    #pragma unroll
    for (int rr = 0; rr < 4; ++rr) {
        acc[rr][0] = bj; acc[rr][1] = 0.f; acc[rr][2] = 0.f; acc[rr][3] = 0.f;
    }

    #pragma unroll 4
    for (int q = 0; q < EMBED / 4; ++q) {
        float4 r0 = e0[q], r1 = e1[q], r2 = e2[q], r3 = e3[q];
        #pragma unroll
        for (int d = 0; d < 4; ++d) {
            float w = WxL[(4 * q + d) * HID + jj];
            acc[0][d] += (&r0.x)[d] * w;
            acc[1][d] += (&r1.x)[d] * w;
            acc[2][d] += (&r2.x)[d] * w;
            acc[3][d] += (&r3.x)[d] * w;
        }
    }
    if (j < HID) {
        #pragma unroll
        for (int rr = 0; rr < 4; ++rr) {
            if (v0 + rr < VOCAB)
                embP[(size_t)(v0 + rr) * HID + j] =
                    (acc[rr][0] + acc[rr][1]) + (acc[rr][2] + acc[rr][3]);
        }
    }
}

// Kernel 2: fused RNN recurrence + dense head.
// Wave = 4 batch rows x 16 lanes; lane (row q4, col jj) computes columns jj
// and jj+16 -- two independent copies of the r7 per-column chain sharing the
// hv reads. LDS h-broadcast volume: 1/4 of r7 (16 lanes/row, 4 rows per
// ds_read_b128). All hL reads via __builtin_memcpy + fences (see header).
// All LDS traffic is wave-private -> no barriers anywhere.
__global__ __launch_bounds__(128, 1) void rnn_head_kernel(
    const int* __restrict__ tokens, const float* __restrict__ embP,
    const float* __restrict__ Wh,
    const float* __restrict__ W1, const float* __restrict__ b1,
    const float* __restrict__ W2, const float* __restrict__ b2,
    const float* __restrict__ W3, const float* __restrict__ b3,
    const float* __restrict__ Wo, const float* __restrict__ bo,
    float* __restrict__ out)
{
    __shared__ int tokL[8][SEQ];
    __shared__ __align__(16) float hL[8][36];   // stride 36 (144B, 16B-aligned rows)
    __shared__ float d1L[8][128];
    __shared__ float d2L[8][64];

    int tid  = threadIdx.x;
    int wv   = tid >> 6;            // wave 0..1
    int l    = tid & 63;
    int q4   = l >> 4;              // row-in-wave 0..3
    int jj   = l & 15;              // column A; column B = jj+16
    int rloc = wv * 4 + q4;         // row within block, 0..7
    int jB   = jj + 16;
    int b    = blockIdx.x * 8 + rloc;

    // stage this row's tokens (wave-private -> in-wave DS order, no barrier)
    for (int i = jj; i < SEQ; i += 16)
        tokL[rloc][i] = tokens[(size_t)b * SEQ + i];

    hL[rloc][jj] = 0.0f;            // h0 = 0
    hL[rloc][jB] = 0.0f;            // cols 30,31 zeroed here, never rewritten
    COMPILER_FENCE();               // init stores precede first hv reads

    float whcA[HID], whcB[HID];
    #pragma unroll
    for (int k = 0; k < HID; ++k) {
        whcA[k] = Wh[k * HID + jj];                      // jj < 16 < 30
        whcB[k] = (jB < HID) ? Wh[k * HID + jB] : 0.0f;  // cols 30,31 -> 0
    }

    bool ldB = (jB < HID);
    // prefetch ring: 8 steps ahead, 2 gathers/lane/step (16 loads in flight)
    float xqA[8], xqB[8];
    #pragma unroll
    for (int s = 0; s < 8; ++s) {
        int tk = tokL[rloc][s];
        xqA[s] = embP[(size_t)tk * HID + jj];
        xqB[s] = ldB ? embP[(size_t)tk * HID + jB] : 0.0f;
    }

    for (int t = 0; t < SEQ; t += 8) {
        #pragma unroll
        for (int s = 0; s < 8; ++s) {
            int tf = t + 8 + s; tf = (tf < SEQ) ? tf : SEQ - 1;
            int tkn = tokL[rloc][tf];

            // 8x ds_read_b128 via memcpy (alias-safe vs the float stores);
            // each read serves all 4 rows of the wave
            float hv[32];
            #pragma unroll
            for (int qq = 0; qq < 8; ++qq) {
                float4 hh;
                __builtin_memcpy(&hh, &hL[rloc][4 * qq], sizeof(float4));
                hv[4*qq+0] = hh.x; hv[4*qq+1] = hh.y;
                hv[4*qq+2] = hh.z; hv[4*qq+3] = hh.w;
            }
            // two columns, each the exact r7 even/odd chain (independent
            // accumulators; no cross-column FP op)
            float a0 = xqA[s], a1 = 0.0f;
            float c0 = xqB[s], c1 = 0.0f;
            #pragma unroll
            for (int k = 0; k < HID; k += 2) {
                a0 += hv[k]     * whcA[k];
                a1 += hv[k + 1] * whcA[k + 1];
                c0 += hv[k]     * whcB[k];
                c1 += hv[k + 1] * whcB[k + 1];
            }
            float hnA = tanh_fast(a0 + a1);
            float hnB = tanh_fast(c0 + c1);   // cols 30,31: tanh(0), write gated
            hL[rloc][jj] = hnA;
            if (ldB) hL[rloc][jB] = hnB;
            COMPILER_FENCE();   // stores of step s precede reads of step s+1

            // refill ring slot for step t+8+s
            xqA[s] = embP[(size_t)tkn * HID + jj];
            xqB[s] = ldB ? embP[(size_t)tkn * HID + jB] : 0.0f;
        }
    }

    // ---- dense head: r7 code per 32-lane half; 2 passes cover 4 rows/wave ----
    int half = l >> 5, l32 = l & 31;
    #pragma unroll
    for (int pp = 0; pp < 2; ++pp) {
        int rh = wv * 4 + half * 2 + pp;     // this wave's rows only
        int bB = blockIdx.x * 8 + rh;
        float hs[HID];
        #pragma unroll
        for (int k = 0; k < HID; ++k) hs[k] = hL[rh][k];

        #pragma unroll
        for (int qq = 0; qq < 4; ++qq) {
            int c = l32 + 32 * qq;
            float acc = b1[c];
            #pragma unroll
            for (int k = 0; k < HID; ++k) acc += hs[k] * W1[k * 128 + c];
            d1L[rh][c] = fmaxf(acc, 0.0f);
        }
        COMPILER_FENCE();
        #pragma unroll
        for (int qq = 0; qq < 2; ++qq) {
            int c = l32 + 32 * qq;
            float acc = b2[c];
            #pragma unroll 8
            for (int k = 0; k < 128; ++k) acc += d1L[rh][k] * W2[k * 64 + c];
            d2L[rh][c] = fmaxf(acc, 0.0f);
        }
        COMPILER_FENCE();
        float acc3 = b3[l32];
        #pragma unroll 8
        for (int k = 0; k < 64; ++k) acc3 += d2L[rh][k] * W3[k * 32 + l32];
        acc3 = fmaxf(acc3, 0.0f);
        float prod = acc3 * Wo[l32];
        #pragma unroll
        for (int m = 16; m > 0; m >>= 1) prod += __shfl_xor(prod, m, 32);
        if (l32 == 0) out[bB] = 1.0f / (1.0f + __expf(-(prod + bo[0])));
        COMPILER_FENCE();
    }
}

extern "C" void kernel_launch(void* const* d_in, const int* in_sizes, int n_in,
                              void* d_out, int out_size, void* d_ws, size_t ws_size,
                              hipStream_t stream) {
    (void)in_sizes; (void)n_in; (void)out_size; (void)ws_size;
    const int*   tokens = (const int*)  d_in[0];
    const float* emb    = (const float*)d_in[1];
    const float* Wx     = (const float*)d_in[2];
    const float* Wh     = (const float*)d_in[3];
    const float* brnn   = (const float*)d_in[4];
    const float* W1     = (const float*)d_in[5];
    const float* b1     = (const float*)d_in[6];
    const float* W2     = (const float*)d_in[7];
    const float* b2     = (const float*)d_in[8];
    const float* W3     = (const float*)d_in[9];
    const float* b3     = (const float*)d_in[10];
    const float* Wo     = (const float*)d_in[11];
    const float* bo     = (const float*)d_in[12];
    float* out  = (float*)d_out;
    float* embP = (float*)d_ws;   // 50000*30*4 = 6 MB

    embproj_kernel<<<(VOCAB + 31) / 32, 256, 0, stream>>>(emb, Wx, brnn, embP);
    rnn_head_kernel<<<BATCH / 8, 128, 0, stream>>>(
        tokens, embP, Wh, W1, b1, W2, b2, W3, b3, Wo, bo, out);
}